// Round 12
// baseline (742.078 us; speedup 1.0000x reference)
//
#include <hip/hip_runtime.h>
#include <hip/hip_bf16.h>
#include <cstdint>
#include <cstddef>

// Problem constants
#define B_DIM   8192
#define OBS_DIM 256
#define ACT_DIM 32
#define HID_DIM 512
#define NEXPERT 8
#define GRID    512   // 2 blocks/CU avg; capacity >= 4/CU at 32KB LDS -> all resident

typedef __attribute__((ext_vector_type(4))) float        f32x4;
typedef __attribute__((ext_vector_type(8))) short        s16x8;   // 8 bf16 in 4 VGPRs
typedef __attribute__((ext_vector_type(4))) unsigned int u32x4;

// v_cvt_pk_bf16_f32: D[15:0]=bf16(lo), D[31:16]=bf16(hi), RNE. No builtin on gfx950.
__device__ __forceinline__ unsigned cvt_pk_bf16(float lo, float hi) {
    unsigned r;
    asm("v_cvt_pk_bf16_f32 %0, %1, %2" : "=v"(r) : "v"(lo), "v"(hi));
    return r;
}
__device__ __forceinline__ float bf16_lo_f32(unsigned u) { return __uint_as_float(u << 16); }
__device__ __forceinline__ float bf16_hi_f32(unsigned u) { return __uint_as_float(u & 0xffff0000u); }

struct MegaArgs {
    const float*    cs[7];
    unsigned short* cd[7];
    int             cnb[7];
    int             ctot;
    const unsigned short *obs_bf, *gw0_bf, *gw1_bf, *gw2_bf, *ew0_bf, *ew1_bf, *ew2_bf;
    const float *gb0, *gb1, *gb2, *eb0, *eb1, *eb2;
    unsigned short *h0, *h1;
    float *blend, *part, *out;
    unsigned *bar;   // 16 counters, memset to 0 before each launch
};

// ---------------------------------------------------------------------------
// Manual grid barrier. One counter per barrier instance (no reset/reuse).
// All GRID blocks are co-resident (32KB LDS -> >=4 blocks/CU capacity, grid
// 512 = 2/CU avg), so the spin always completes; timeout guards a hang.
// Device-scope atomicAdd [m20] + agent-scope fences for cross-XCD visibility.
// ---------------------------------------------------------------------------
__device__ __forceinline__ void grid_barrier(unsigned* ctr) {
    __syncthreads();                        // all block threads' writes issued+drained
    if (threadIdx.x == 0) {
        __threadfence();                    // release: my writes visible device-wide
        atomicAdd(ctr, 1u);
        const long long t0 = clock64();
        while (__hip_atomic_load(ctr, __ATOMIC_RELAXED, __HIP_MEMORY_SCOPE_AGENT)
               < (unsigned)GRID) {
            __builtin_amdgcn_s_sleep(2);
            if (clock64() - t0 > (1LL << 26)) break;   // bounded: fail clean, no hang
        }
        __threadfence();                    // acquire: see others' writes
    }
    __syncthreads();
}

// ---------------------------------------------------------------------------
// Stage: fp32 -> bf16 bulk convert, grid-stride.
// ---------------------------------------------------------------------------
__device__ void cvt_stage(int b, const MegaArgs& a) {
    const int t = threadIdx.x;
    for (int vb = b; vb < a.ctot; vb += GRID) {
        int seg = 0, base = 0;
        while (seg < 6 && vb >= base + a.cnb[seg]) { base += a.cnb[seg]; ++seg; }
        const int local = (vb - base) * 256 + t;
        const f32x4* s = (const f32x4*)a.cs[seg];
        f32x4 v0 = s[local * 2 + 0];
        f32x4 v1 = s[local * 2 + 1];
        u32x4 o;
        o[0] = cvt_pk_bf16(v0[0], v0[1]);
        o[1] = cvt_pk_bf16(v0[2], v0[3]);
        o[2] = cvt_pk_bf16(v1[0], v1[1]);
        o[3] = cvt_pk_bf16(v1[2], v1[3]);
        ((u32x4*)a.cd[seg])[local] = o;
    }
}

// ---------------------------------------------------------------------------
// Stage: gate GEMM (R2/R3-proven single-buffer loop): BM=128 BN=64 BK=64,
// bias+relu -> bf16. b -> (m=b&63, n=b>>6), grid 64x8 = 512.  LDS 24KB.
// ---------------------------------------------------------------------------
template <int KIN, int NOUT>
__device__ void gate_stage(int b, const unsigned short* __restrict__ A,
                           const unsigned short* __restrict__ W,
                           const float* __restrict__ bias,
                           unsigned short* __restrict__ outb,
                           unsigned char* SMEM) {
    constexpr int BM = 128, BN = 64, BK = 64;
    unsigned short* sA = (unsigned short*)SMEM;                  // 16 KB
    unsigned short* sB = (unsigned short*)(SMEM + BM * BK * 2);  //  8 KB

    const int t    = threadIdx.x;
    const int lane = t & 63;
    const int wid  = t >> 6;
    const int wm   = wid >> 1, wn = wid & 1;
    const int m0   = (b & 63) * BM;
    const int n0   = (b >> 6) * BN;

    f32x4 acc[4][2];
#pragma unroll
    for (int i = 0; i < 4; ++i)
#pragma unroll
        for (int j = 0; j < 2; ++j) acc[i][j] = {0.f, 0.f, 0.f, 0.f};

#pragma unroll 1
    for (int kt = 0; kt < KIN / BK; ++kt) {
        const int ks = kt * BK;
        __syncthreads();
        const unsigned short* Wp = W + (size_t)n0 * KIN + ks;
#pragma unroll
        for (int c = 0; c < 2; ++c) {
            const int ch  = c * 256 + t;
            const int row = ch >> 3;
            const int gs  = (ch & 7) ^ (row & 7);
            __builtin_amdgcn_global_load_lds(
                (const __attribute__((address_space(1))) unsigned int*)(Wp + (size_t)row * KIN + gs * 8),
                (__attribute__((address_space(3))) unsigned int*)(sB + ch * 8), 16, 0, 0);
        }
        const unsigned short* Ap = A + (size_t)m0 * KIN + ks;
#pragma unroll
        for (int c = 0; c < 4; ++c) {
            const int ch  = c * 256 + t;
            const int row = ch >> 3;
            const int gs  = (ch & 7) ^ (row & 7);
            __builtin_amdgcn_global_load_lds(
                (const __attribute__((address_space(1))) unsigned int*)(Ap + (size_t)row * KIN + gs * 8),
                (__attribute__((address_space(3))) unsigned int*)(sA + ch * 8), 16, 0, 0);
        }
        __syncthreads();

#pragma unroll
        for (int kk = 0; kk < BK; kk += 32) {
            const int kb = kk + ((lane >> 4) << 3);
            s16x8 af[4], bfr[2];
#pragma unroll
            for (int mf = 0; mf < 4; ++mf) {
                const int row = wm * 64 + mf * 16 + (lane & 15);
                const int idx = (row * BK + kb) ^ ((row & 7) << 3);
                af[mf] = *(const s16x8*)(sA + idx);
            }
#pragma unroll
            for (int nf = 0; nf < 2; ++nf) {
                const int row = wn * 32 + nf * 16 + (lane & 15);
                const int idx = (row * BK + kb) ^ ((row & 7) << 3);
                bfr[nf] = *(const s16x8*)(sB + idx);
            }
#pragma unroll
            for (int mf = 0; mf < 4; ++mf)
#pragma unroll
                for (int nf = 0; nf < 2; ++nf)
                    acc[mf][nf] = __builtin_amdgcn_mfma_f32_16x16x32_bf16(af[mf], bfr[nf],
                                                                          acc[mf][nf], 0, 0, 0);
        }
    }

    const int cn = lane & 15;
    const int rb = (lane >> 4) << 2;
#pragma unroll
    for (int nf = 0; nf < 2; ++nf) {
        const int gn   = n0 + wn * 32 + nf * 16 + cn;
        const float bv = bias[gn];
#pragma unroll
        for (int mf = 0; mf < 4; ++mf) {
#pragma unroll
            for (int r = 0; r < 4; ++r) {
                const int gm = m0 + wm * 64 + mf * 16 + rb + r;
                float v = fmaxf(acc[mf][nf][r] + bv, 0.f);
                outb[(size_t)gm * NOUT + gn] = (unsigned short)(cvt_pk_bf16(v, v) & 0xffffu);
            }
        }
    }
}

// ---------------------------------------------------------------------------
// Stage: gate softmax head. Grid-stride over 2048 virtual blocks (4 rows each).
// ---------------------------------------------------------------------------
__device__ void softmax_stage(int b, const unsigned short* __restrict__ h1,
                              const unsigned short* __restrict__ gw2,
                              const float* __restrict__ gb2,
                              float* __restrict__ blend) {
    const int lane = threadIdx.x & 63;
    const int wid  = threadIdx.x >> 6;
    for (int vb = b; vb < B_DIM / 4; vb += GRID) {
        const int row = vb * 4 + wid;
        u32x4 xv = *(const u32x4*)(h1 + (size_t)row * HID_DIM + lane * 8);
        float x[8];
#pragma unroll
        for (int j = 0; j < 4; ++j) {
            unsigned u   = xv[j];
            x[2 * j]     = bf16_lo_f32(u);
            x[2 * j + 1] = bf16_hi_f32(u);
        }
        float s[NEXPERT];
#pragma unroll
        for (int pp = 0; pp < NEXPERT; ++pp) {
            u32x4 wv = *(const u32x4*)(gw2 + (size_t)pp * HID_DIM + lane * 8);
            float d  = 0.f;
#pragma unroll
            for (int j = 0; j < 4; ++j) {
                unsigned u = wv[j];
                d += x[2 * j] * bf16_lo_f32(u);
                d += x[2 * j + 1] * bf16_hi_f32(u);
            }
            s[pp] = d;
        }
#pragma unroll
        for (int off = 1; off < 64; off <<= 1) {
#pragma unroll
            for (int pp = 0; pp < NEXPERT; ++pp) s[pp] += __shfl_xor(s[pp], off);
        }
        if (lane == 0) {
            float l[NEXPERT], m = -1e30f;
#pragma unroll
            for (int pp = 0; pp < NEXPERT; ++pp) { l[pp] = s[pp] + gb2[pp]; m = fmaxf(m, l[pp]); }
            float sum = 0.f;
#pragma unroll
            for (int pp = 0; pp < NEXPERT; ++pp) { l[pp] = __expf(l[pp] - m); sum += l[pp]; }
            float inv = 1.f / sum;
#pragma unroll
            for (int pp = 0; pp < NEXPERT; ++pp) blend[(size_t)row * NEXPERT + pp] = l[pp] * inv;
        }
    }
}

// ---------------------------------------------------------------------------
// Stage: expert GEMM (R3-proven single-buffer loop), split-K, dual-acc fold
// with blend from global, pre-blended fp32 partial out.  LDS 32KB (BN=128).
// NOUT==HID: b -> (m=b&63, n=(b>>6)&3, sp=b>>8)   [grid 64x4x2]
// NOUT==64 : b -> (m=b&63, n=0,        sp=b>>6)   [grid 64x8]
// ---------------------------------------------------------------------------
template <int KIN, int NOUT, int BN, int TPB>
__device__ void moe_stage(int b, const unsigned short* __restrict__ A,
                          const unsigned short* __restrict__ W,
                          const float* __restrict__ blend,
                          float* __restrict__ part,
                          unsigned char* SMEM) {
    constexpr int BM  = 128, BK = 64;
    constexpr int NF  = BN / 32;
    constexpr int TPE = KIN / BK;
    constexpr int NPE = (TPB >= TPE) ? TPB / TPE : 1;
    constexpr int ET  = (TPB >= TPE) ? TPE : TPB;
    static_assert((TPB % TPE == 0) || (TPE % TPB == 0), "split/expert alignment");

    unsigned short* sA = (unsigned short*)SMEM;                  // 16 KB
    unsigned short* sB = (unsigned short*)(SMEM + BM * BK * 2);  // 16/8 KB

    const int t    = threadIdx.x;
    const int lane = t & 63;
    const int wid  = t >> 6;
    const int wm   = wid >> 1, wn = wid & 1;
    const int m0 = (b & 63) * BM;
    const int n0 = (NOUT == 64) ? 0 : ((b >> 6) & 3) * BN;
    const int sp = (NOUT == 64) ? (b >> 6) : (b >> 8);

    const int cn = lane & 15;
    const int rb = (lane >> 4) << 2;

    f32x4 mast[4][NF];
#pragma unroll
    for (int i = 0; i < 4; ++i)
#pragma unroll
        for (int j = 0; j < NF; ++j) mast[i][j] = {0.f, 0.f, 0.f, 0.f};

#pragma unroll 1
    for (int pe = 0; pe < NPE; ++pe) {
        const int tbase = sp * TPB + pe * ET;
        const int p     = tbase / TPE;
        const int ksb   = (tbase % TPE) * BK;

        f32x4 eacc[4][NF];
#pragma unroll
        for (int i = 0; i < 4; ++i)
#pragma unroll
            for (int j = 0; j < NF; ++j) eacc[i][j] = {0.f, 0.f, 0.f, 0.f};

        const unsigned short* Ap0 = A + (size_t)m0 * KIN + ksb;
        const unsigned short* Wp0 = W + ((size_t)p * NOUT + n0) * KIN + ksb;

#pragma unroll 1
        for (int kt = 0; kt < ET; ++kt) {
            const int ks = kt * BK;
            __syncthreads();
#pragma unroll
            for (int c = 0; c < NF; ++c) {
                const int ch  = c * 256 + t;
                const int row = ch >> 3;
                const int gs  = (ch & 7) ^ (row & 7);
                __builtin_amdgcn_global_load_lds(
                    (const __attribute__((address_space(1))) unsigned int*)(Wp0 + (size_t)row * KIN + ks + gs * 8),
                    (__attribute__((address_space(3))) unsigned int*)(sB + ch * 8), 16, 0, 0);
            }
#pragma unroll
            for (int c = 0; c < 4; ++c) {
                const int ch  = c * 256 + t;
                const int row = ch >> 3;
                const int gs  = (ch & 7) ^ (row & 7);
                __builtin_amdgcn_global_load_lds(
                    (const __attribute__((address_space(1))) unsigned int*)(Ap0 + (size_t)row * KIN + ks + gs * 8),
                    (__attribute__((address_space(3))) unsigned int*)(sA + ch * 8), 16, 0, 0);
            }
            __syncthreads();

#pragma unroll
            for (int kk = 0; kk < BK; kk += 32) {
                const int kb = kk + ((lane >> 4) << 3);
                s16x8 af[4], bfr[NF];
#pragma unroll
                for (int mf = 0; mf < 4; ++mf) {
                    const int row = wm * 64 + mf * 16 + (lane & 15);
                    const int idx = (row * BK + kb) ^ ((row & 7) << 3);
                    af[mf] = *(const s16x8*)(sA + idx);
                }
#pragma unroll
                for (int nf = 0; nf < NF; ++nf) {
                    const int row = wn * (BN / 2) + nf * 16 + (lane & 15);
                    const int idx = (row * BK + kb) ^ ((row & 7) << 3);
                    bfr[nf] = *(const s16x8*)(sB + idx);
                }
#pragma unroll
                for (int mf = 0; mf < 4; ++mf)
#pragma unroll
                    for (int nf = 0; nf < NF; ++nf)
                        eacc[mf][nf] = __builtin_amdgcn_mfma_f32_16x16x32_bf16(af[mf], bfr[nf],
                                                                               eacc[mf][nf], 0, 0, 0);
            }
        }

        // fold expert into master: mast += blend[b,p] * eacc (blend from global)
#pragma unroll
        for (int mf = 0; mf < 4; ++mf) {
#pragma unroll
            for (int r = 0; r < 4; ++r) {
                const int gm = m0 + wm * 64 + mf * 16 + rb + r;
                const float bl = blend[(size_t)gm * NEXPERT + p];
#pragma unroll
                for (int nf = 0; nf < NF; ++nf)
                    mast[mf][nf][r] += bl * eacc[mf][nf][r];
            }
        }
    }

    float* dst = part + (size_t)sp * B_DIM * NOUT;
#pragma unroll
    for (int mf = 0; mf < 4; ++mf) {
#pragma unroll
        for (int r = 0; r < 4; ++r) {
            const int gm = m0 + wm * 64 + mf * 16 + rb + r;
#pragma unroll
            for (int nf = 0; nf < NF; ++nf) {
                const int gn = n0 + wn * (BN / 2) + nf * 16 + cn;
                dst[(size_t)gm * NOUT + gn] = mast[mf][nf][r];
            }
        }
    }
}

// ---------------------------------------------------------------------------
// Stage: reduce 2 fp32 partials + blended bias + relu -> bf16. Grid-stride.
// ---------------------------------------------------------------------------
__device__ void reduce2_stage(int b, const float* __restrict__ part,
                              const float* __restrict__ blend,
                              const float* __restrict__ eb,
                              unsigned short* __restrict__ out) {
    for (int vb = b; vb < B_DIM * 64 / 256; vb += GRID) {
        const int tid = vb * 256 + threadIdx.x;
        const int row = tid >> 6;
        const int c0  = (tid & 63) << 3;

        const f32x4* p0 = (const f32x4*)(part + (size_t)row * HID_DIM + c0);
        const f32x4* p1 = (const f32x4*)(part + ((size_t)B_DIM + row) * HID_DIM + c0);
        f32x4 v0 = p0[0], v1 = p0[1], w0 = p1[0], w1 = p1[1];

        const f32x4* bl = (const f32x4*)(blend + (size_t)row * NEXPERT);
        const f32x4 b0 = bl[0], b1 = bl[1];
        const float blv[8] = {b0[0], b0[1], b0[2], b0[3], b1[0], b1[1], b1[2], b1[3]};

        float res[8];
#pragma unroll
        for (int j = 0; j < 4; ++j) { res[j] = v0[j] + w0[j]; res[4 + j] = v1[j] + w1[j]; }
#pragma unroll
        for (int pp = 0; pp < NEXPERT; ++pp) {
            const f32x4* e = (const f32x4*)(eb + (size_t)pp * HID_DIM + c0);
            const f32x4 e0 = e[0], e1 = e[1];
#pragma unroll
            for (int j = 0; j < 4; ++j) {
                res[j]     += blv[pp] * e0[j];
                res[4 + j] += blv[pp] * e1[j];
            }
        }
        u32x4 o;
#pragma unroll
        for (int j = 0; j < 4; ++j)
            o[j] = cvt_pk_bf16(fmaxf(res[2 * j], 0.f), fmaxf(res[2 * j + 1], 0.f));
        *(u32x4*)(out + (size_t)row * HID_DIM + c0) = o;
    }
}

// ---------------------------------------------------------------------------
// Stage: reduce 8 fp32 partials + blended bias + mu/std head -> f32.
// ---------------------------------------------------------------------------
__device__ void reduce8_stage(int b, const float* __restrict__ part,
                              const float* __restrict__ blend,
                              const float* __restrict__ eb2,
                              float* __restrict__ out) {
    for (int vb = b; vb < B_DIM * 8 / 256; vb += GRID) {
        const int tid = vb * 256 + threadIdx.x;
        const int row = tid >> 3;
        const int c0  = (tid & 7) << 3;

        float res[8] = {0.f, 0.f, 0.f, 0.f, 0.f, 0.f, 0.f, 0.f};
#pragma unroll
        for (int sp = 0; sp < 8; ++sp) {
            const f32x4* ps = (const f32x4*)(part + ((size_t)sp * B_DIM + row) * 64 + c0);
            const f32x4 a = ps[0], bb = ps[1];
#pragma unroll
            for (int j = 0; j < 4; ++j) { res[j] += a[j]; res[4 + j] += bb[j]; }
        }
        const f32x4* bl = (const f32x4*)(blend + (size_t)row * NEXPERT);
        const f32x4 b0 = bl[0], b1 = bl[1];
        const float blv[8] = {b0[0], b0[1], b0[2], b0[3], b1[0], b1[1], b1[2], b1[3]};
#pragma unroll
        for (int pp = 0; pp < NEXPERT; ++pp) {
            const f32x4* e = (const f32x4*)(eb2 + (size_t)pp * 64 + c0);
            const f32x4 e0 = e[0], e1 = e[1];
#pragma unroll
            for (int j = 0; j < 4; ++j) {
                res[j]     += blv[pp] * e0[j];
                res[4 + j] += blv[pp] * e1[j];
            }
        }
        f32x4 o0, o1;
#pragma unroll
        for (int j = 0; j < 8; ++j) {
            const int col = c0 + j;
            float v = res[j];
            if (col >= ACT_DIM) {
                const float vc = fminf(fmaxf(v, -15.f), 15.f);
                const float e2 = __expf(2.f * vc);
                const float th = (e2 - 1.f) / (e2 + 1.f);
                v = __expf(-1.5f + 3.5f * th);
            }
            if (j < 4) o0[j] = v; else o1[j - 4] = v;
        }
        f32x4* dst = (f32x4*)(out + (size_t)row * 64 + c0);
        dst[0] = o0;
        dst[1] = o1;
    }
}

// ---------------------------------------------------------------------------
// The mega kernel: all 10 stages, manual grid barrier between them.
// Normal launch (no cooperative API). 32KB LDS -> >=4 blocks/CU capacity.
// ---------------------------------------------------------------------------
__global__ __launch_bounds__(256, 2) void mega(MegaArgs a) {
    __shared__ __align__(16) unsigned char SMEM[32768];
    const int b = blockIdx.x;

    cvt_stage(b, a);
    grid_barrier(&a.bar[0]);
    gate_stage<OBS_DIM, HID_DIM>(b, a.obs_bf, a.gw0_bf, a.gb0, a.h0, SMEM);
    grid_barrier(&a.bar[1]);
    gate_stage<HID_DIM, HID_DIM>(b, a.h0, a.gw1_bf, a.gb1, a.h1, SMEM);
    grid_barrier(&a.bar[2]);
    softmax_stage(b, a.h1, a.gw2_bf, a.gb2, a.blend);
    grid_barrier(&a.bar[3]);
    // E0: K=2048 (TPE=4), split-2 -> TPB=16 = 4 experts/block
    moe_stage<OBS_DIM, HID_DIM, 128, 16>(b, a.obs_bf, a.ew0_bf, a.blend, a.part, SMEM);
    grid_barrier(&a.bar[4]);
    reduce2_stage(b, a.part, a.blend, a.eb0, a.h0);
    grid_barrier(&a.bar[5]);
    // E1: K=4096 (TPE=8), split-2 -> TPB=32 = 4 experts/block
    moe_stage<HID_DIM, HID_DIM, 128, 32>(b, a.h0, a.ew1_bf, a.blend, a.part, SMEM);
    grid_barrier(&a.bar[6]);
    reduce2_stage(b, a.part, a.blend, a.eb1, a.h1);
    grid_barrier(&a.bar[7]);
    // E2: K=4096 (TPE=8), split-8 -> TPB=8 = 1 expert/block
    moe_stage<HID_DIM, 64, 64, 8>(b, a.h1, a.ew2_bf, a.blend, a.part, SMEM);
    grid_barrier(&a.bar[8]);
    reduce8_stage(b, a.part, a.blend, a.eb2, a.out);
}

// ---------------------------------------------------------------------------
extern "C" void kernel_launch(void* const* d_in, const int* in_sizes, int n_in,
                              void* d_out, int out_size, void* d_ws, size_t ws_size,
                              hipStream_t stream) {
    const float* obs = (const float*)d_in[0];
    const float* gw0 = (const float*)d_in[1];
    const float* gb0 = (const float*)d_in[2];
    const float* gw1 = (const float*)d_in[3];
    const float* gb1 = (const float*)d_in[4];
    const float* gw2 = (const float*)d_in[5];
    const float* gb2 = (const float*)d_in[6];
    const float* ew0 = (const float*)d_in[7];
    const float* eb0 = (const float*)d_in[8];
    const float* ew1 = (const float*)d_in[9];
    const float* eb1 = (const float*)d_in[10];
    const float* ew2 = (const float*)d_in[11];
    const float* eb2 = (const float*)d_in[12];

    char* w = (char*)d_ws;
    auto alloc = [&](size_t bytes) {
        char* r = w;
        w += (bytes + 255) & ~(size_t)255;
        return r;
    };
    unsigned*       bar    = (unsigned*)alloc(16 * sizeof(unsigned));
    unsigned short* obs_bf = (unsigned short*)alloc((size_t)B_DIM * OBS_DIM * 2);
    unsigned short* gw0_bf = (unsigned short*)alloc((size_t)HID_DIM * OBS_DIM * 2);
    unsigned short* gw1_bf = (unsigned short*)alloc((size_t)HID_DIM * HID_DIM * 2);
    unsigned short* gw2_bf = (unsigned short*)alloc((size_t)NEXPERT * HID_DIM * 2);
    unsigned short* ew0_bf = (unsigned short*)alloc((size_t)NEXPERT * HID_DIM * OBS_DIM * 2);
    unsigned short* ew1_bf = (unsigned short*)alloc((size_t)NEXPERT * HID_DIM * HID_DIM * 2);
    unsigned short* ew2_bf = (unsigned short*)alloc((size_t)NEXPERT * 2 * ACT_DIM * HID_DIM * 2);
    unsigned short* h0     = (unsigned short*)alloc((size_t)B_DIM * HID_DIM * 2);
    unsigned short* h1     = (unsigned short*)alloc((size_t)B_DIM * HID_DIM * 2);
    float*          blend  = (float*)alloc((size_t)B_DIM * NEXPERT * 4);
    // 32 MB: split-2 x B x HID f32 partials; also covers E2's 8 x B x 64.
    float*          part   = (float*)alloc((size_t)2 * B_DIM * HID_DIM * 4);

    // barrier counters must start at 0 every call (ws is poisoned 0xAA)
    hipMemsetAsync(bar, 0, 16 * sizeof(unsigned), stream);

    MegaArgs ma;
    ma.cs[0] = obs; ma.cd[0] = obs_bf; ma.cnb[0] = (B_DIM * OBS_DIM / 8) / 256;
    ma.cs[1] = gw0; ma.cd[1] = gw0_bf; ma.cnb[1] = (HID_DIM * OBS_DIM / 8) / 256;
    ma.cs[2] = gw1; ma.cd[2] = gw1_bf; ma.cnb[2] = (HID_DIM * HID_DIM / 8) / 256;
    ma.cs[3] = gw2; ma.cd[3] = gw2_bf; ma.cnb[3] = (NEXPERT * HID_DIM / 8) / 256;
    ma.cs[4] = ew0; ma.cd[4] = ew0_bf; ma.cnb[4] = (NEXPERT * HID_DIM * OBS_DIM / 8) / 256;
    ma.cs[5] = ew1; ma.cd[5] = ew1_bf; ma.cnb[5] = (NEXPERT * HID_DIM * HID_DIM / 8) / 256;
    ma.cs[6] = ew2; ma.cd[6] = ew2_bf; ma.cnb[6] = (NEXPERT * 64 * HID_DIM / 8) / 256;
    ma.ctot = 0;
    for (int i = 0; i < 7; ++i) ma.ctot += ma.cnb[i];
    ma.obs_bf = obs_bf; ma.gw0_bf = gw0_bf; ma.gw1_bf = gw1_bf; ma.gw2_bf = gw2_bf;
    ma.ew0_bf = ew0_bf; ma.ew1_bf = ew1_bf; ma.ew2_bf = ew2_bf;
    ma.gb0 = gb0; ma.gb1 = gb1; ma.gb2 = gb2;
    ma.eb0 = eb0; ma.eb1 = eb1; ma.eb2 = eb2;
    ma.h0 = h0; ma.h1 = h1;
    ma.blend = blend; ma.part = part; ma.out = (float*)d_out;
    ma.bar = bar;

    mega<<<dim3(GRID), dim3(256), 0, stream>>>(ma);
}